// Round 3
// baseline (258.626 us; speedup 1.0000x reference)
//
#include <hip/hip_runtime.h>

// PyramidROIAlign, v2.1 (v2 with ext_vector_type for nontemporal stores).
// One 256-thread block (4 waves) per box; grid = B*N = 2000 blocks -> whole
// grid co-resident (8 blocks/CU x 4 waves = 32 waves/CU, full occupancy).
// Wave `w` handles pool cells {w, w+4, ...} of its box, TWO cells per loop
// iteration => 8 independent float4 gathers in flight per wave.
// Lane t covers channels [4t, 4t+4). NHWC => each corner is a contiguous
// 1KB run (perfectly coalesced). Output stores are nontemporal so the
// 100MB write stream doesn't evict the L3-resident feature maps.

typedef float f4 __attribute__((ext_vector_type(4)));

__global__ __launch_bounds__(256, 8) void roi_align_kernel(
    const float* __restrict__ boxes,   // (B,N,4) y1,x1,y2,x2
    const float* __restrict__ meta,    // (B,14); meta[4],meta[5] = img H,W
    const float* __restrict__ f2,      // (B,256,256,256)
    const float* __restrict__ f3,      // (B,128,128,256)
    const float* __restrict__ f4_,     // (B, 64, 64,256)
    const float* __restrict__ f5,      // (B, 32, 32,256)
    float* __restrict__ out,           // (B,N,7,7,256)
    int N)
{
    const int C = 256;
    int bn   = blockIdx.x;             // box id in [0, B*N)
    int b    = bn / N;
    int wave = threadIdx.x >> 6;
    int lane = threadIdx.x & 63;

    // ---- per-box setup (uniform; once per thread, not once per cell) ----
    float y1 = boxes[bn * 4 + 0];
    float x1 = boxes[bn * 4 + 1];
    float y2 = boxes[bn * 4 + 2];
    float x2 = boxes[bn * 4 + 3];
    float h = y2 - y1;
    float w = x2 - x1;

    float area = meta[4] * meta[5];
    float lvl  = log2f(sqrtf(h * w) / (224.0f / sqrtf(area)));
    float rl   = fminf(fmaxf(4.0f + rintf(lvl), 2.0f), 5.0f); // -inf -> 2
    int level  = (int)rl;

    const float* fm;
    int H;
    if (level == 2)      { fm = f2;  H = 256; }
    else if (level == 3) { fm = f3;  H = 128; }
    else if (level == 4) { fm = f4_; H = 64;  }
    else                 { fm = f5;  H = 32;  }
    const int W = H;

    float Hm1 = (float)(H - 1);
    float sy = (h * Hm1) / 6.0f;       // match reference fp32 op order
    float sx = (w * Hm1) / 6.0f;
    float yb = y1 * Hm1;
    float xb = x1 * Hm1;

    const float* fmb  = fm  + (size_t)b  * H * W * C + lane * 4;
    float*       outb = out + (size_t)bn * 49 * C    + lane * 4;

    // compute 4 corner pointers + fracs for one pool cell
    auto cell_setup = [&](int c, const f4*& tl, const f4*& tr,
                          const f4*& bl, const f4*& br, float& fx, float& fy) {
        int py = c / 7;
        int px = c - py * 7;
        float ys = yb + (float)py * sy;
        float xs = xb + (float)px * sx;
        float y0f = floorf(ys);
        float x0f = floorf(xs);
        fy = ys - y0f;
        fx = xs - x0f;
        int y0 = min(max((int)y0f, 0), H - 1);
        int x0 = min(max((int)x0f, 0), W - 1);
        int yi = min(y0 + 1, H - 1);
        int xi = min(x0 + 1, W - 1);
        tl = (const f4*)(fmb + (y0 * W + x0) * C);
        tr = (const f4*)(fmb + (y0 * W + xi) * C);
        bl = (const f4*)(fmb + (yi * W + x0) * C);
        br = (const f4*)(fmb + (yi * W + xi) * C);
    };

    auto lerp4 = [](f4 tl, f4 tr, f4 bl, f4 br, float fx, float fy) {
        f4 top = tl + (tr - tl) * fx;
        f4 bot = bl + (br - bl) * fx;
        return top + (bot - top) * fy;
    };

    // cells wave, wave+4, ... two per iteration for memory-level parallelism
    #pragma unroll 1
    for (int i = 0; i < 7; ++i) {
        int cA = wave + i * 8;
        int cB = cA + 4;
        bool doA = (cA < 49);          // wave-uniform guards
        bool doB = (cB < 49);

        f4 tlA{}, trA{}, blA{}, brA{}, tlB{}, trB{}, blB{}, brB{};
        float fxA = 0.f, fyA = 0.f, fxB = 0.f, fyB = 0.f;

        if (doA) {
            const f4 *ptl, *ptr_, *pbl, *pbr;
            cell_setup(cA, ptl, ptr_, pbl, pbr, fxA, fyA);
            tlA = *ptl; trA = *ptr_; blA = *pbl; brA = *pbr;
        }
        if (doB) {
            const f4 *ptl, *ptr_, *pbl, *pbr;
            cell_setup(cB, ptl, ptr_, pbl, pbr, fxB, fyB);
            tlB = *ptl; trB = *ptr_; blB = *pbl; brB = *pbr;
        }

        if (doA) {
            f4 o = lerp4(tlA, trA, blA, brA, fxA, fyA);
            __builtin_nontemporal_store(o, (f4*)(outb + cA * C));
        }
        if (doB) {
            f4 o = lerp4(tlB, trB, blB, brB, fxB, fyB);
            __builtin_nontemporal_store(o, (f4*)(outb + cB * C));
        }
    }
}

extern "C" void kernel_launch(void* const* d_in, const int* in_sizes, int n_in,
                              void* d_out, int out_size, void* d_ws, size_t ws_size,
                              hipStream_t stream) {
    const float* boxes = (const float*)d_in[0];
    const float* meta  = (const float*)d_in[1];
    const float* f2    = (const float*)d_in[2];
    const float* f3    = (const float*)d_in[3];
    const float* f4_   = (const float*)d_in[4];
    const float* f5    = (const float*)d_in[5];
    float* out = (float*)d_out;

    int B = in_sizes[1] / 14;            // image_meta is (B,14)
    int N = in_sizes[0] / (4 * B);       // boxes is (B,N,4)

    int grid = B * N;                    // one 4-wave block per box
    roi_align_kernel<<<grid, 256, 0, stream>>>(boxes, meta, f2, f3, f4_, f5, out, N);
}

// Round 4
// 257.986 us; speedup vs baseline: 1.0025x; 1.0025x over previous
//
#include <hip/hip_runtime.h>

// PyramidROIAlign, v3.
// - One 256-thread block (4 waves) per box; grid = B*N. Wave w sweeps cells
//   {w, w+4, ...}: ONE cell per iteration (4 live f4 regs -> ~45 VGPR, no
//   spills under the 64-VGPR/8-block budget; 32 waves/CU).
// - BW analysis: 392 MB irreducible gathers + 100 MB writes; f4/f5 (75% of
//   gathers, 10.5 MB) live in L2/L3; f2/f3 gathers are sparse over 167 MB ->
//   loaded NONTEMPORAL so they don't evict the hot f4/f5 set from L2.
// - Output (100 MB, write-once) stored nontemporal.
// Lane t covers channels [4t,4t+4); NHWC => each corner is a contiguous,
// perfectly-coalesced 1KB wave transaction.

typedef float f4 __attribute__((ext_vector_type(4)));

__global__ __launch_bounds__(256, 8) void roi_align_kernel(
    const float* __restrict__ boxes,   // (B,N,4) y1,x1,y2,x2
    const float* __restrict__ meta,    // (B,14); meta[4],meta[5] = img H,W
    const float* __restrict__ f2,      // (B,256,256,256)
    const float* __restrict__ f3,      // (B,128,128,256)
    const float* __restrict__ f4_,     // (B, 64, 64,256)
    const float* __restrict__ f5,      // (B, 32, 32,256)
    float* __restrict__ out,           // (B,N,7,7,256)
    int N)
{
    const int C = 256;
    int bn   = blockIdx.x;             // box id in [0, B*N)
    int b    = bn / N;
    int wave = threadIdx.x >> 6;
    int lane = threadIdx.x & 63;

    // ---- per-box setup (wave-uniform) ----
    float y1 = boxes[bn * 4 + 0];
    float x1 = boxes[bn * 4 + 1];
    float y2 = boxes[bn * 4 + 2];
    float x2 = boxes[bn * 4 + 3];
    float h = y2 - y1;
    float w = x2 - x1;

    float area = meta[4] * meta[5];
    float lvl  = log2f(sqrtf(h * w) / (224.0f / sqrtf(area)));
    float rl   = fminf(fmaxf(4.0f + rintf(lvl), 2.0f), 5.0f); // -inf -> 2
    int level  = (int)rl;

    const float* fm;
    int H;
    if (level == 2)      { fm = f2;  H = 256; }
    else if (level == 3) { fm = f3;  H = 128; }
    else if (level == 4) { fm = f4_; H = 64;  }
    else                 { fm = f5;  H = 32;  }
    const int W = H;
    const bool big_map = (H >= 128);   // f2/f3: sparse, reuse-free -> bypass

    float Hm1 = (float)(H - 1);
    float sy = (h * Hm1) / 6.0f;       // match reference fp32 op order
    float sx = (w * Hm1) / 6.0f;
    float yb = y1 * Hm1;
    float xb = x1 * Hm1;

    const float* fmb  = fm  + (size_t)b  * H * W * C + lane * 4;
    float*       outb = out + (size_t)bn * 49 * C    + lane * 4;

    // cells wave, wave+4, ... (49 cells over 4 waves -> 13 iterations)
    #pragma unroll 1
    for (int c = wave; c < 49; c += 4) {
        int py = c / 7;
        int px = c - py * 7;
        float ys = yb + (float)py * sy;
        float xs = xb + (float)px * sx;
        float y0f = floorf(ys);
        float x0f = floorf(xs);
        float fy = ys - y0f;
        float fx = xs - x0f;
        int y0 = min(max((int)y0f, 0), H - 1);
        int x0 = min(max((int)x0f, 0), W - 1);
        int yi = min(y0 + 1, H - 1);
        int xi = min(x0 + 1, W - 1);

        const f4* ptl = (const f4*)(fmb + (y0 * W + x0) * C);
        const f4* ptr_ = (const f4*)(fmb + (y0 * W + xi) * C);
        const f4* pbl = (const f4*)(fmb + (yi * W + x0) * C);
        const f4* pbr = (const f4*)(fmb + (yi * W + xi) * C);

        f4 tl, tr, bl, br;
        if (big_map) {                 // wave-uniform branch
            tl = __builtin_nontemporal_load(ptl);
            tr = __builtin_nontemporal_load(ptr_);
            bl = __builtin_nontemporal_load(pbl);
            br = __builtin_nontemporal_load(pbr);
        } else {
            tl = *ptl; tr = *ptr_; bl = *pbl; br = *pbr;
        }

        f4 top = tl + (tr - tl) * fx;
        f4 bot = bl + (br - bl) * fx;
        f4 o   = top + (bot - top) * fy;
        __builtin_nontemporal_store(o, (f4*)(outb + c * C));
    }
}

extern "C" void kernel_launch(void* const* d_in, const int* in_sizes, int n_in,
                              void* d_out, int out_size, void* d_ws, size_t ws_size,
                              hipStream_t stream) {
    const float* boxes = (const float*)d_in[0];
    const float* meta  = (const float*)d_in[1];
    const float* f2    = (const float*)d_in[2];
    const float* f3    = (const float*)d_in[3];
    const float* f4_   = (const float*)d_in[4];
    const float* f5    = (const float*)d_in[5];
    float* out = (float*)d_out;

    int B = in_sizes[1] / 14;            // image_meta is (B,14)
    int N = in_sizes[0] / (4 * B);       // boxes is (B,N,4)

    int grid = B * N;                    // one 4-wave block per box
    roi_align_kernel<<<grid, 256, 0, stream>>>(boxes, meta, f2, f3, f4_, f5, out, N);
}